// Round 1
// baseline (158.588 us; speedup 1.0000x reference)
//
#include <hip/hip_runtime.h>

#define EPS 1e-5f

typedef unsigned short u16;
typedef __attribute__((ext_vector_type(8))) __bf16 bf16x8;
typedef __attribute__((ext_vector_type(4))) float f32x4;
typedef __attribute__((ext_vector_type(8))) unsigned short ushort8;

__device__ inline float bf2f(u16 h) {
  union { unsigned u; float f; } x; x.u = ((unsigned)h) << 16; return x.f;
}
__device__ inline u16 f2bf(float f) {
  union { float f; unsigned u; } x; x.f = f;
  unsigned r = x.u + 0x7fffu + ((x.u >> 16) & 1u);
  return (u16)(r >> 16);
}
__device__ inline float sigmoidf(float x) { return 1.0f / (1.0f + __expf(-x)); }

// ---------------- cast: 4 equal-size f32 -> bf16(u16) arrays ----------------
__global__ __launch_bounds__(256) void cast4_f32_bf16(
    const float* __restrict__ s0, const float* __restrict__ s1,
    const float* __restrict__ s2, const float* __restrict__ s3,
    u16* __restrict__ d0, u16* __restrict__ d1,
    u16* __restrict__ d2, u16* __restrict__ d3, int n)
{
  const float* s = (blockIdx.y == 0) ? s0 : (blockIdx.y == 1) ? s1 : (blockIdx.y == 2) ? s2 : s3;
  u16*         d = (blockIdx.y == 0) ? d0 : (blockIdx.y == 1) ? d1 : (blockIdx.y == 2) ? d2 : d3;
  int i = (blockIdx.x * 256 + threadIdx.x) * 8;
  if (i >= n) return;
  float4 a = *(const float4*)(s + i);
  float4 b = *(const float4*)(s + i + 4);
  ushort8 o;
  o[0] = f2bf(a.x); o[1] = f2bf(a.y); o[2] = f2bf(a.z); o[3] = f2bf(a.w);
  o[4] = f2bf(b.x); o[5] = f2bf(b.y); o[6] = f2bf(b.z); o[7] = f2bf(b.w);
  *(ushort8*)(d + i) = o;
}

// ---------------- GEMM: C[m][n] = sum_k A[m][k] * W[n][k], bf16 in/out, f32 acc
// m97 structure: 128x128 tile, BK=32, 4 waves (2x2), 16x16x32 MFMA,
// global_load_lds width=16 staging.
__global__ __launch_bounds__(256) void gemm_bt_bf16(
    const u16* __restrict__ A, const u16* __restrict__ W,
    u16* __restrict__ C, int M, int N, int K)
{
  __shared__ __attribute__((aligned(16))) u16 sA[128 * 32];
  __shared__ __attribute__((aligned(16))) u16 sB[128 * 32];

  const int tid = threadIdx.x;
  const int l = tid & 63;
  const int w = tid >> 6;
  const int wr = w >> 1, wc = w & 1;

  const int nbn = N / 128;
  const int bm = (blockIdx.x / nbn) * 128;
  const int bn = (blockIdx.x % nbn) * 128;

  // staging geometry: chunk q (=p*4+w) covers rows [q*16, q*16+16), 1024B each
  const int srow = l >> 2;          // row within chunk
  const int scol = (l & 3) * 8;     // element column (8 bf16 = 16B)

  f32x4 acc[4][4] = {};

  const u16* pA = A + (size_t)bm * K;
  const u16* pB = W + (size_t)bn * K;

  for (int k0 = 0; k0 < K; k0 += 32) {
#pragma unroll
    for (int p = 0; p < 2; ++p) {
      int q = p * 4 + w;
      int r = q * 16 + srow;
      const u16* srcA = pA + (size_t)r * K + k0 + scol;
      const u16* srcB = pB + (size_t)r * K + k0 + scol;
      __builtin_amdgcn_global_load_lds(
          (const __attribute__((address_space(1))) void*)srcA,
          (__attribute__((address_space(3))) void*)(sA + q * 512), 16, 0, 0);
      __builtin_amdgcn_global_load_lds(
          (const __attribute__((address_space(1))) void*)srcB,
          (__attribute__((address_space(3))) void*)(sB + q * 512), 16, 0, 0);
    }
    __syncthreads();

    bf16x8 af[4], bfr[4];
#pragma unroll
    for (int mi = 0; mi < 4; ++mi) {
      int row = wr * 64 + mi * 16 + (l & 15);
      af[mi] = *(const bf16x8*)(sA + row * 32 + (l >> 4) * 8);
    }
#pragma unroll
    for (int ni = 0; ni < 4; ++ni) {
      int row = wc * 64 + ni * 16 + (l & 15);
      bfr[ni] = *(const bf16x8*)(sB + row * 32 + (l >> 4) * 8);
    }
#pragma unroll
    for (int mi = 0; mi < 4; ++mi)
#pragma unroll
      for (int ni = 0; ni < 4; ++ni)
        acc[mi][ni] = __builtin_amdgcn_mfma_f32_16x16x32_bf16(
            af[mi], bfr[ni], acc[mi][ni], 0, 0, 0);
    __syncthreads();
  }

  // C/D layout (m89/m91 verified): col = lane&15, row = (lane>>4)*4 + reg
#pragma unroll
  for (int mi = 0; mi < 4; ++mi) {
#pragma unroll
    for (int ni = 0; ni < 4; ++ni) {
      int col = bn + wc * 64 + ni * 16 + (l & 15);
#pragma unroll
      for (int r = 0; r < 4; ++r) {
        int row = bm + wr * 64 + mi * 16 + (l >> 4) * 4 + r;
        C[(size_t)row * N + col] = f2bf(acc[mi][ni][r]);
      }
    }
  }
}

// ---------------- fused LN(ig) + LN(hg) + gates + cell-LN + outputs ----------
// one block (256 threads) per batch row b.
__global__ __launch_bounds__(256) void lstm_epilogue(
    const u16* __restrict__ ig, const u16* __restrict__ hg,
    const float* __restrict__ cx,
    const float* __restrict__ gi, const float* __restrict__ bi,
    const float* __restrict__ gh, const float* __restrict__ bh,
    const float* __restrict__ gc, const float* __restrict__ bc,
    float* __restrict__ out)
{
  const int b = blockIdx.x;
  const int t = threadIdx.x;
  const u16* igr = ig + (size_t)b * 4096;
  const u16* hgr = hg + (size_t)b * 4096;

  __shared__ float redbuf[16];

  float iv[16], hv[16];
  float s_i = 0.f, q_i = 0.f, s_h = 0.f, q_h = 0.f;
#pragma unroll
  for (int i = 0; i < 16; ++i) {
    float a = bf2f(igr[t + 256 * i]);
    float c = bf2f(hgr[t + 256 * i]);
    iv[i] = a; hv[i] = c;
    s_i += a; q_i += a * a; s_h += c; q_h += c * c;
  }
  // block reduce 4 values
#pragma unroll
  for (int off = 32; off > 0; off >>= 1) {
    s_i += __shfl_xor(s_i, off);
    q_i += __shfl_xor(q_i, off);
    s_h += __shfl_xor(s_h, off);
    q_h += __shfl_xor(q_h, off);
  }
  {
    int wv = t >> 6;
    if ((t & 63) == 0) {
      redbuf[wv] = s_i; redbuf[wv + 4] = q_i;
      redbuf[wv + 8] = s_h; redbuf[wv + 12] = q_h;
    }
    __syncthreads();
    s_i = redbuf[0] + redbuf[1] + redbuf[2] + redbuf[3];
    q_i = redbuf[4] + redbuf[5] + redbuf[6] + redbuf[7];
    s_h = redbuf[8] + redbuf[9] + redbuf[10] + redbuf[11];
    q_h = redbuf[12] + redbuf[13] + redbuf[14] + redbuf[15];
    __syncthreads();
  }
  const float inv4096 = 1.0f / 4096.0f;
  float mu_i = s_i * inv4096;
  float rs_i = rsqrtf(q_i * inv4096 - mu_i * mu_i + EPS);
  float mu_h = s_h * inv4096;
  float rs_h = rsqrtf(q_h * inv4096 - mu_h * mu_h + EPS);

  float c_pre[4], og[4];
  float s_c = 0.f, q_c = 0.f;
#pragma unroll
  for (int i = 0; i < 4; ++i) {
    int h = t + 256 * i;
    // gate g lives at j = h + 1024*g = t + 256*(i + 4g)  ->  local index i + 4g
    float g_in = ((iv[i]      - mu_i) * rs_i * gi[h]        + bi[h]) +
                 ((hv[i]      - mu_h) * rs_h * gh[h]        + bh[h]);
    float g_fg = ((iv[i + 4]  - mu_i) * rs_i * gi[h + 1024] + bi[h + 1024]) +
                 ((hv[i + 4]  - mu_h) * rs_h * gh[h + 1024] + bh[h + 1024]);
    float g_cl = ((iv[i + 8]  - mu_i) * rs_i * gi[h + 2048] + bi[h + 2048]) +
                 ((hv[i + 8]  - mu_h) * rs_h * gh[h + 2048] + bh[h + 2048]);
    float g_og = ((iv[i + 12] - mu_i) * rs_i * gi[h + 3072] + bi[h + 3072]) +
                 ((hv[i + 12] - mu_h) * rs_h * gh[h + 3072] + bh[h + 3072]);
    float in_s = sigmoidf(g_in);
    float fg_s = sigmoidf(g_fg);
    float cl_t = tanhf(g_cl);
    og[i] = sigmoidf(g_og);
    c_pre[i] = fg_s * cx[(size_t)b * 1024 + h] + in_s * cl_t;
    s_c += c_pre[i]; q_c += c_pre[i] * c_pre[i];
  }
  // block reduce 2 values
#pragma unroll
  for (int off = 32; off > 0; off >>= 1) {
    s_c += __shfl_xor(s_c, off);
    q_c += __shfl_xor(q_c, off);
  }
  {
    int wv = t >> 6;
    if ((t & 63) == 0) { redbuf[wv] = s_c; redbuf[wv + 4] = q_c; }
    __syncthreads();
    s_c = redbuf[0] + redbuf[1] + redbuf[2] + redbuf[3];
    q_c = redbuf[4] + redbuf[5] + redbuf[6] + redbuf[7];
  }
  const float inv1024 = 1.0f / 1024.0f;
  float mu_c = s_c * inv1024;
  float rs_c = rsqrtf(q_c * inv1024 - mu_c * mu_c + EPS);

  const size_t BH = (size_t)4096 * 1024;
#pragma unroll
  for (int i = 0; i < 4; ++i) {
    int h = t + 256 * i;
    float cy = (c_pre[i] - mu_c) * rs_c * gc[h] + bc[h];
    float hy = og[i] * tanhf(cy);
    size_t o = (size_t)b * 1024 + h;
    out[o] = hy;
    out[BH + o] = hy;
    out[2 * BH + o] = cy;
  }
}

extern "C" void kernel_launch(void* const* d_in, const int* in_sizes, int n_in,
                              void* d_out, int out_size, void* d_ws, size_t ws_size,
                              hipStream_t stream) {
  const float* input = (const float*)d_in[0];
  const float* hx    = (const float*)d_in[1];
  const float* cx    = (const float*)d_in[2];
  const float* wih   = (const float*)d_in[3];
  const float* whh   = (const float*)d_in[4];
  const float* gi    = (const float*)d_in[5];
  const float* bi    = (const float*)d_in[6];
  const float* gh    = (const float*)d_in[7];
  const float* bh    = (const float*)d_in[8];
  const float* gc    = (const float*)d_in[9];
  const float* bc    = (const float*)d_in[10];
  float* out = (float*)d_out;

  char* w = (char*)d_ws;
  u16* a_bf  = (u16*)(w);                       // 8 MB  input bf16
  u16* h_bf  = (u16*)(w + ((size_t)8  << 20));  // 8 MB  hx bf16
  u16* wi_bf = (u16*)(w + ((size_t)16 << 20));  // 8 MB  weight_ih bf16
  u16* wh_bf = (u16*)(w + ((size_t)24 << 20));  // 8 MB  weight_hh bf16
  u16* ig_bf = (u16*)(w + ((size_t)32 << 20));  // 32 MB raw igates bf16
  u16* hg_bf = (u16*)(w + ((size_t)64 << 20));  // 32 MB raw hgates bf16

  const int nper = 4096 * 1024;  // all four cast arrays are 4M elements
  dim3 cgrid(nper / 8 / 256, 4);
  cast4_f32_bf16<<<cgrid, 256, 0, stream>>>(input, hx, wih, whh,
                                            a_bf, h_bf, wi_bf, wh_bf, nper);

  gemm_bt_bf16<<<1024, 256, 0, stream>>>(a_bf, wi_bf, ig_bf, 4096, 4096, 1024);
  gemm_bt_bf16<<<1024, 256, 0, stream>>>(h_bf, wh_bf, hg_bf, 4096, 4096, 1024);

  lstm_epilogue<<<4096, 256, 0, stream>>>(ig_bf, hg_bf, cx,
                                          gi, bi, gh, bh, gc, bc, out);
}

// Round 2
// 134.009 us; speedup vs baseline: 1.1834x; 1.1834x over previous
//
#include <hip/hip_runtime.h>

#define EPS 1e-5f

typedef unsigned short u16;
typedef __attribute__((ext_vector_type(8))) __bf16 bf16x8;
typedef __attribute__((ext_vector_type(4))) float f32x4;
typedef __attribute__((ext_vector_type(8))) unsigned short ushort8;

__device__ inline float bf2f(u16 h) {
  union { unsigned u; float f; } x; x.u = ((unsigned)h) << 16; return x.f;
}
__device__ inline u16 f2bf(float f) {
  union { float f; unsigned u; } x; x.f = f;
  unsigned r = x.u + 0x7fffu + ((x.u >> 16) & 1u);
  return (u16)(r >> 16);
}
__device__ inline float sigmoidf(float x) { return 1.0f / (1.0f + __expf(-x)); }

// ---------------- cast: 4 equal-size f32 -> bf16(u16) arrays ----------------
__global__ __launch_bounds__(256) void cast4_f32_bf16(
    const float* __restrict__ s0, const float* __restrict__ s1,
    const float* __restrict__ s2, const float* __restrict__ s3,
    u16* __restrict__ d0, u16* __restrict__ d1,
    u16* __restrict__ d2, u16* __restrict__ d3, int n)
{
  const float* s = (blockIdx.y == 0) ? s0 : (blockIdx.y == 1) ? s1 : (blockIdx.y == 2) ? s2 : s3;
  u16*         d = (blockIdx.y == 0) ? d0 : (blockIdx.y == 1) ? d1 : (blockIdx.y == 2) ? d2 : d3;
  int i = (blockIdx.x * 256 + threadIdx.x) * 8;
  if (i >= n) return;
  float4 a = *(const float4*)(s + i);
  float4 b = *(const float4*)(s + i + 4);
  ushort8 o;
  o[0] = f2bf(a.x); o[1] = f2bf(a.y); o[2] = f2bf(a.z); o[3] = f2bf(a.w);
  o[4] = f2bf(b.x); o[5] = f2bf(b.y); o[6] = f2bf(b.z); o[7] = f2bf(b.w);
  *(ushort8*)(d + i) = o;
}

// ---------------- GEMM: C[m][n] = sum_k A[m][k] * W[n][k] -------------------
// 256x256 tile, BK=64, 512 threads (8 waves, 2Mx4N), 128 KiB LDS double-buffer,
// 4-phase-per-K-tile schedule (T3-style): per phase {stage-issue | ds_read frag
// | s_barrier | setprio(1) 16xMFMA setprio(0) | s_barrier}; staging issued in
// phases 0-1 stays in flight across barriers, drained once per tile boundary.
// LDS swizzle (T2-equivalent): 16B slot s at row r holds global k8 = s^(r&7);
// staged via pre-swizzled GLOBAL source + linear global_load_lds dest.
#define MFMA_ __builtin_amdgcn_mfma_f32_16x16x32_bf16

#define STAGE_A(nx, k0) { _Pragma("unroll") for (int i_ = 0; i_ < 4; ++i_) \
  __builtin_amdgcn_global_load_lds( \
      (const __attribute__((address_space(1))) void*)(gA + (size_t)(i_ * 64) * K + (k0)), \
      (__attribute__((address_space(3))) void*)(&sA[nx][(i_ * 512 + (w << 6)) * 8]), 16, 0, 0); }
#define STAGE_B(nx, k0) { _Pragma("unroll") for (int i_ = 0; i_ < 4; ++i_) \
  __builtin_amdgcn_global_load_lds( \
      (const __attribute__((address_space(1))) void*)(gB + (size_t)(i_ * 64) * K + (k0)), \
      (__attribute__((address_space(3))) void*)(&sB[nx][(i_ * 512 + (w << 6)) * 8]), 16, 0, 0); }

#define LDA(mi, sl) (*(const bf16x8*)&sa[(arow + (mi) * 16) * 64 + (sl)])
#define LDB(ni, sl) (*(const bf16x8*)&sb[(brow + (ni) * 16) * 64 + (sl)])

// one phase: 4 A-frag reads (+4 B-frag reads if RB), barrier, 16 MFMA
#define PHASE(m0, sl, RB) { \
  bf16x8 a0 = LDA(m0 + 0, sl), a1 = LDA(m0 + 1, sl), a2 = LDA(m0 + 2, sl), a3 = LDA(m0 + 3, sl); \
  if (RB) { q0 = LDB(0, sl); q1 = LDB(1, sl); q2 = LDB(2, sl); q3 = LDB(3, sl); } \
  __builtin_amdgcn_s_barrier(); \
  __builtin_amdgcn_s_setprio(1); \
  acc[m0 + 0][0] = MFMA_(a0, q0, acc[m0 + 0][0], 0, 0, 0); \
  acc[m0 + 0][1] = MFMA_(a0, q1, acc[m0 + 0][1], 0, 0, 0); \
  acc[m0 + 0][2] = MFMA_(a0, q2, acc[m0 + 0][2], 0, 0, 0); \
  acc[m0 + 0][3] = MFMA_(a0, q3, acc[m0 + 0][3], 0, 0, 0); \
  acc[m0 + 1][0] = MFMA_(a1, q0, acc[m0 + 1][0], 0, 0, 0); \
  acc[m0 + 1][1] = MFMA_(a1, q1, acc[m0 + 1][1], 0, 0, 0); \
  acc[m0 + 1][2] = MFMA_(a1, q2, acc[m0 + 1][2], 0, 0, 0); \
  acc[m0 + 1][3] = MFMA_(a1, q3, acc[m0 + 1][3], 0, 0, 0); \
  acc[m0 + 2][0] = MFMA_(a2, q0, acc[m0 + 2][0], 0, 0, 0); \
  acc[m0 + 2][1] = MFMA_(a2, q1, acc[m0 + 2][1], 0, 0, 0); \
  acc[m0 + 2][2] = MFMA_(a2, q2, acc[m0 + 2][2], 0, 0, 0); \
  acc[m0 + 2][3] = MFMA_(a2, q3, acc[m0 + 2][3], 0, 0, 0); \
  acc[m0 + 3][0] = MFMA_(a3, q0, acc[m0 + 3][0], 0, 0, 0); \
  acc[m0 + 3][1] = MFMA_(a3, q1, acc[m0 + 3][1], 0, 0, 0); \
  acc[m0 + 3][2] = MFMA_(a3, q2, acc[m0 + 3][2], 0, 0, 0); \
  acc[m0 + 3][3] = MFMA_(a3, q3, acc[m0 + 3][3], 0, 0, 0); \
  __builtin_amdgcn_s_setprio(0); }

__global__ __launch_bounds__(512, 2) void gemm256_dual(
    const u16* __restrict__ A0, const u16* __restrict__ W0, u16* __restrict__ C0,
    const u16* __restrict__ A1, const u16* __restrict__ W1, u16* __restrict__ C1)
{
  constexpr int K = 1024, N = 4096, NT = 16;  // K-tiles of 64

  __shared__ __attribute__((aligned(16))) u16 sA[2][256 * 64];  // 2 x 32 KiB
  __shared__ __attribute__((aligned(16))) u16 sB[2][256 * 64];  // 2 x 32 KiB

  const int bid = blockIdx.x;
  const u16* A  = (bid < 256) ? A0 : A1;
  const u16* Wm = (bid < 256) ? W0 : W1;
  u16*       C  = (bid < 256) ? C0 : C1;
  const int b2 = bid & 255;
  const int bm = (b2 >> 4) << 8;
  const int bn = (b2 & 15) << 8;

  const int tid = threadIdx.x;
  const int l  = tid & 63;
  const int w  = tid >> 6;   // wave 0..7
  const int wr = w >> 2;     // 0..1  -> M offset wr*128
  const int wc = w & 3;      // 0..3  -> N offset wc*64

  // staging: thread tid, chunk i -> LDS row i*64 + (tid>>3), slot tid&7 (linear);
  // global source column pre-swizzled: k8_src = (tid&7) ^ (row&7)
  const int rb   = tid >> 3;
  const int slot = (tid & 7) ^ (rb & 7);
  const u16* gA = A  + (size_t)(bm + rb) * K + slot * 8;
  const u16* gB = Wm + (size_t)(bn + rb) * K + slot * 8;

  // fragment read addressing (swizzled): elem = row*64 + ((k8 ^ (row&7))*8)
  const int arow = wr * 128 + (l & 15);
  const int brow = wc * 64 + (l & 15);
  const int sl0 = (((l >> 4) + 0) ^ (l & 7)) * 8;  // ks=0: k8 = l>>4
  const int sl1 = (((l >> 4) + 4) ^ (l & 7)) * 8;  // ks=1: k8 = 4 + (l>>4)

  f32x4 acc[8][4];
#pragma unroll
  for (int i = 0; i < 8; ++i)
#pragma unroll
    for (int j = 0; j < 4; ++j) acc[i][j] = (f32x4){0.f, 0.f, 0.f, 0.f};

  // prologue: stage K-tile 0 into buffer 0
  STAGE_A(0, 0)
  STAGE_B(0, 0)
  __syncthreads();

  for (int t = 0; t < NT; ++t) {
    const int cur = t & 1, nxt = cur ^ 1;
    const int kn = (t + 1) << 6;
    const u16* sa = sA[cur];
    const u16* sb = sB[cur];
    bf16x8 q0, q1, q2, q3;

    if (t < NT - 1) STAGE_A(nxt, kn)     // phase 0: issue A prefetch
    PHASE(0, sl0, 1)                      // mi 0-3, ks 0 (reads B ks0)
    __builtin_amdgcn_s_barrier();
    if (t < NT - 1) STAGE_B(nxt, kn)     // phase 1: issue B prefetch
    PHASE(4, sl0, 0)                      // mi 4-7, ks 0
    __builtin_amdgcn_s_barrier();
    PHASE(0, sl1, 1)                      // mi 0-3, ks 1 (reads B ks1)
    __builtin_amdgcn_s_barrier();
    PHASE(4, sl1, 0)                      // mi 4-7, ks 1
    __syncthreads();                      // boundary: drain vmcnt, flip buffers
  }

  // C write: col = lane&15, row = (lane>>4)*4 + reg  (m89/m91-verified layout)
  const int ccol = bn + wc * 64 + (l & 15);
  const int crow = bm + wr * 128 + (l >> 4) * 4;
#pragma unroll
  for (int mi = 0; mi < 8; ++mi) {
#pragma unroll
    for (int ni = 0; ni < 4; ++ni) {
      int col = ccol + ni * 16;
#pragma unroll
      for (int r = 0; r < 4; ++r) {
        int row = crow + mi * 16 + r;
        C[(size_t)row * N + col] = f2bf(acc[mi][ni][r]);
      }
    }
  }
}

// ---------------- fused LN(ig) + LN(hg) + gates + cell-LN + outputs ----------
__global__ __launch_bounds__(256) void lstm_epilogue(
    const u16* __restrict__ ig, const u16* __restrict__ hg,
    const float* __restrict__ cx,
    const float* __restrict__ gi, const float* __restrict__ bi,
    const float* __restrict__ gh, const float* __restrict__ bh,
    const float* __restrict__ gc, const float* __restrict__ bc,
    float* __restrict__ out)
{
  const int b = blockIdx.x;
  const int t = threadIdx.x;
  const u16* igr = ig + (size_t)b * 4096;
  const u16* hgr = hg + (size_t)b * 4096;

  __shared__ float redbuf[16];

  float iv[16], hv[16];
  float s_i = 0.f, q_i = 0.f, s_h = 0.f, q_h = 0.f;
#pragma unroll
  for (int i = 0; i < 16; ++i) {
    float a = bf2f(igr[t + 256 * i]);
    float c = bf2f(hgr[t + 256 * i]);
    iv[i] = a; hv[i] = c;
    s_i += a; q_i += a * a; s_h += c; q_h += c * c;
  }
#pragma unroll
  for (int off = 32; off > 0; off >>= 1) {
    s_i += __shfl_xor(s_i, off);
    q_i += __shfl_xor(q_i, off);
    s_h += __shfl_xor(s_h, off);
    q_h += __shfl_xor(q_h, off);
  }
  {
    int wv = t >> 6;
    if ((t & 63) == 0) {
      redbuf[wv] = s_i; redbuf[wv + 4] = q_i;
      redbuf[wv + 8] = s_h; redbuf[wv + 12] = q_h;
    }
    __syncthreads();
    s_i = redbuf[0] + redbuf[1] + redbuf[2] + redbuf[3];
    q_i = redbuf[4] + redbuf[5] + redbuf[6] + redbuf[7];
    s_h = redbuf[8] + redbuf[9] + redbuf[10] + redbuf[11];
    q_h = redbuf[12] + redbuf[13] + redbuf[14] + redbuf[15];
    __syncthreads();
  }
  const float inv4096 = 1.0f / 4096.0f;
  float mu_i = s_i * inv4096;
  float rs_i = rsqrtf(q_i * inv4096 - mu_i * mu_i + EPS);
  float mu_h = s_h * inv4096;
  float rs_h = rsqrtf(q_h * inv4096 - mu_h * mu_h + EPS);

  float c_pre[4], og[4];
  float s_c = 0.f, q_c = 0.f;
#pragma unroll
  for (int i = 0; i < 4; ++i) {
    int h = t + 256 * i;
    float g_in = ((iv[i]      - mu_i) * rs_i * gi[h]        + bi[h]) +
                 ((hv[i]      - mu_h) * rs_h * gh[h]        + bh[h]);
    float g_fg = ((iv[i + 4]  - mu_i) * rs_i * gi[h + 1024] + bi[h + 1024]) +
                 ((hv[i + 4]  - mu_h) * rs_h * gh[h + 1024] + bh[h + 1024]);
    float g_cl = ((iv[i + 8]  - mu_i) * rs_i * gi[h + 2048] + bi[h + 2048]) +
                 ((hv[i + 8]  - mu_h) * rs_h * gh[h + 2048] + bh[h + 2048]);
    float g_og = ((iv[i + 12] - mu_i) * rs_i * gi[h + 3072] + bi[h + 3072]) +
                 ((hv[i + 12] - mu_h) * rs_h * gh[h + 3072] + bh[h + 3072]);
    float in_s = sigmoidf(g_in);
    float fg_s = sigmoidf(g_fg);
    float cl_t = tanhf(g_cl);
    og[i] = sigmoidf(g_og);
    c_pre[i] = fg_s * cx[(size_t)b * 1024 + h] + in_s * cl_t;
    s_c += c_pre[i]; q_c += c_pre[i] * c_pre[i];
  }
#pragma unroll
  for (int off = 32; off > 0; off >>= 1) {
    s_c += __shfl_xor(s_c, off);
    q_c += __shfl_xor(q_c, off);
  }
  {
    int wv = t >> 6;
    if ((t & 63) == 0) { redbuf[wv] = s_c; redbuf[wv + 4] = q_c; }
    __syncthreads();
    s_c = redbuf[0] + redbuf[1] + redbuf[2] + redbuf[3];
    q_c = redbuf[4] + redbuf[5] + redbuf[6] + redbuf[7];
  }
  const float inv1024 = 1.0f / 1024.0f;
  float mu_c = s_c * inv1024;
  float rs_c = rsqrtf(q_c * inv1024 - mu_c * mu_c + EPS);

  const size_t BH = (size_t)4096 * 1024;
#pragma unroll
  for (int i = 0; i < 4; ++i) {
    int h = t + 256 * i;
    float cy = (c_pre[i] - mu_c) * rs_c * gc[h] + bc[h];
    float hy = og[i] * tanhf(cy);
    size_t o = (size_t)b * 1024 + h;
    out[o] = hy;
    out[BH + o] = hy;
    out[2 * BH + o] = cy;
  }
}

extern "C" void kernel_launch(void* const* d_in, const int* in_sizes, int n_in,
                              void* d_out, int out_size, void* d_ws, size_t ws_size,
                              hipStream_t stream) {
  const float* input = (const float*)d_in[0];
  const float* hx    = (const float*)d_in[1];
  const float* cx    = (const float*)d_in[2];
  const float* wih   = (const float*)d_in[3];
  const float* whh   = (const float*)d_in[4];
  const float* gi    = (const float*)d_in[5];
  const float* bi    = (const float*)d_in[6];
  const float* gh    = (const float*)d_in[7];
  const float* bh    = (const float*)d_in[8];
  const float* gc    = (const float*)d_in[9];
  const float* bc    = (const float*)d_in[10];
  float* out = (float*)d_out;

  char* wsp = (char*)d_ws;
  u16* a_bf  = (u16*)(wsp);
  u16* h_bf  = (u16*)(wsp + ((size_t)8  << 20));
  u16* wi_bf = (u16*)(wsp + ((size_t)16 << 20));
  u16* wh_bf = (u16*)(wsp + ((size_t)24 << 20));
  u16* ig_bf = (u16*)(wsp + ((size_t)32 << 20));
  u16* hg_bf = (u16*)(wsp + ((size_t)64 << 20));

  const int nper = 4096 * 1024;
  dim3 cgrid(nper / 8 / 256, 4);
  cast4_f32_bf16<<<cgrid, 256, 0, stream>>>(input, hx, wih, whh,
                                            a_bf, h_bf, wi_bf, wh_bf, nper);

  gemm256_dual<<<512, 512, 0, stream>>>(a_bf, wi_bf, ig_bf,
                                        h_bf, wh_bf, hg_bf);

  lstm_epilogue<<<4096, 256, 0, stream>>>(ig_bf, hg_bf, cx,
                                          gi, bi, gh, bh, gc, bc, out);
}

// Round 3
// 125.163 us; speedup vs baseline: 1.2670x; 1.0707x over previous
//
#include <hip/hip_runtime.h>

#define EPS 1e-5f

typedef unsigned short u16;
typedef __attribute__((ext_vector_type(8))) __bf16 bf16x8;
typedef __attribute__((ext_vector_type(4))) float f32x4;
typedef __attribute__((ext_vector_type(8))) unsigned short ushort8;

__device__ inline float bf2f(u16 h) {
  union { unsigned u; float f; } x; x.u = ((unsigned)h) << 16; return x.f;
}
__device__ inline u16 f2bf(float f) {
  union { float f; unsigned u; } x; x.f = f;
  unsigned r = x.u + 0x7fffu + ((x.u >> 16) & 1u);
  return (u16)(r >> 16);
}
__device__ inline float sigmoidf(float x) { return 1.0f / (1.0f + __expf(-x)); }

// ---------------- cast: 4 equal-size f32 -> bf16(u16) arrays ----------------
__global__ __launch_bounds__(256) void cast4_f32_bf16(
    const float* __restrict__ s0, const float* __restrict__ s1,
    const float* __restrict__ s2, const float* __restrict__ s3,
    u16* __restrict__ d0, u16* __restrict__ d1,
    u16* __restrict__ d2, u16* __restrict__ d3, int n)
{
  const float* s = (blockIdx.y == 0) ? s0 : (blockIdx.y == 1) ? s1 : (blockIdx.y == 2) ? s2 : s3;
  u16*         d = (blockIdx.y == 0) ? d0 : (blockIdx.y == 1) ? d1 : (blockIdx.y == 2) ? d2 : d3;
  int i = (blockIdx.x * 256 + threadIdx.x) * 8;
  if (i >= n) return;
  float4 a = *(const float4*)(s + i);
  float4 b = *(const float4*)(s + i + 4);
  ushort8 o;
  o[0] = f2bf(a.x); o[1] = f2bf(a.y); o[2] = f2bf(a.z); o[3] = f2bf(a.w);
  o[4] = f2bf(b.x); o[5] = f2bf(b.y); o[6] = f2bf(b.z); o[7] = f2bf(b.w);
  *(ushort8*)(d + i) = o;
}

// ---------------- GEMM: C[m][n] = sum_k A[m][k] * W[n][k] -------------------
// 256x256 tile, BK=64, 512 threads (8 waves, 2Mx4N), 128 KiB LDS double-buffer.
// T3+T4: 4 phases per K-tile; A-prefetch issued at phase 1, B-prefetch after
// phase 1; the ONLY wait in the main loop is s_waitcnt vmcnt(4) (tile t landed,
// tile t+1's A still in flight). Last tile peeled with vmcnt(0).
// T2: LDS 16B-slot swizzle slot = k8 ^ (row&7), staged via pre-swizzled global
// source + linear global_load_lds dest (rule 21). T1: bijective XCD swizzle.
#define MFMA_ __builtin_amdgcn_mfma_f32_16x16x32_bf16

#define STAGE_A(nx, k0) { _Pragma("unroll") for (int i_ = 0; i_ < 4; ++i_) \
  __builtin_amdgcn_global_load_lds( \
      (const __attribute__((address_space(1))) void*)(gA + (size_t)(i_ * 64) * K + (k0)), \
      (__attribute__((address_space(3))) void*)(&sA[nx][(i_ * 512 + (w << 6)) * 8]), 16, 0, 0); }
#define STAGE_B(nx, k0) { _Pragma("unroll") for (int i_ = 0; i_ < 4; ++i_) \
  __builtin_amdgcn_global_load_lds( \
      (const __attribute__((address_space(1))) void*)(gB + (size_t)(i_ * 64) * K + (k0)), \
      (__attribute__((address_space(3))) void*)(&sB[nx][(i_ * 512 + (w << 6)) * 8]), 16, 0, 0); }

#define LDA(mi, sl) (*(const bf16x8*)&sa[(arow + (mi) * 16) * 64 + (sl)])
#define LDB(ni, sl) (*(const bf16x8*)&sb[(brow + (ni) * 16) * 64 + (sl)])

#define MFMA16(m0) \
  __builtin_amdgcn_s_setprio(1); \
  acc[m0 + 0][0] = MFMA_(a0, q0, acc[m0 + 0][0], 0, 0, 0); \
  acc[m0 + 0][1] = MFMA_(a0, q1, acc[m0 + 0][1], 0, 0, 0); \
  acc[m0 + 0][2] = MFMA_(a0, q2, acc[m0 + 0][2], 0, 0, 0); \
  acc[m0 + 0][3] = MFMA_(a0, q3, acc[m0 + 0][3], 0, 0, 0); \
  acc[m0 + 1][0] = MFMA_(a1, q0, acc[m0 + 1][0], 0, 0, 0); \
  acc[m0 + 1][1] = MFMA_(a1, q1, acc[m0 + 1][1], 0, 0, 0); \
  acc[m0 + 1][2] = MFMA_(a1, q2, acc[m0 + 1][2], 0, 0, 0); \
  acc[m0 + 1][3] = MFMA_(a1, q3, acc[m0 + 1][3], 0, 0, 0); \
  acc[m0 + 2][0] = MFMA_(a2, q0, acc[m0 + 2][0], 0, 0, 0); \
  acc[m0 + 2][1] = MFMA_(a2, q1, acc[m0 + 2][1], 0, 0, 0); \
  acc[m0 + 2][2] = MFMA_(a2, q2, acc[m0 + 2][2], 0, 0, 0); \
  acc[m0 + 2][3] = MFMA_(a2, q3, acc[m0 + 2][3], 0, 0, 0); \
  acc[m0 + 3][0] = MFMA_(a3, q0, acc[m0 + 3][0], 0, 0, 0); \
  acc[m0 + 3][1] = MFMA_(a3, q1, acc[m0 + 3][1], 0, 0, 0); \
  acc[m0 + 3][2] = MFMA_(a3, q2, acc[m0 + 3][2], 0, 0, 0); \
  acc[m0 + 3][3] = MFMA_(a3, q3, acc[m0 + 3][3], 0, 0, 0); \
  __builtin_amdgcn_s_setprio(0);

// reads BEFORE internal barrier (phases 2-4)
#define PHASE(m0, sl, RB) { \
  bf16x8 a0 = LDA(m0 + 0, sl), a1 = LDA(m0 + 1, sl), a2 = LDA(m0 + 2, sl), a3 = LDA(m0 + 3, sl); \
  if (RB) { q0 = LDB(0, sl); q1 = LDB(1, sl); q2 = LDB(2, sl); q3 = LDB(3, sl); } \
  __builtin_amdgcn_s_barrier(); \
  MFMA16(m0) }

// reads AFTER caller's vmcnt+barrier (phase 1: buffer just landed)
#define PHASE_NOBAR(m0, sl, RB) { \
  bf16x8 a0 = LDA(m0 + 0, sl), a1 = LDA(m0 + 1, sl), a2 = LDA(m0 + 2, sl), a3 = LDA(m0 + 3, sl); \
  if (RB) { q0 = LDB(0, sl); q1 = LDB(1, sl); q2 = LDB(2, sl); q3 = LDB(3, sl); } \
  MFMA16(m0) }

__global__ __launch_bounds__(512, 2) void gemm256_dual(
    const u16* __restrict__ A0, const u16* __restrict__ W0, u16* __restrict__ C0,
    const u16* __restrict__ A1, const u16* __restrict__ W1, u16* __restrict__ C1)
{
  constexpr int K = 1024, N = 4096, NT = 16;  // K-tiles of 64

  __shared__ __attribute__((aligned(16))) u16 sA[2][256 * 64];  // 2 x 32 KiB
  __shared__ __attribute__((aligned(16))) u16 sB[2][256 * 64];  // 2 x 32 KiB

  // T1: bijective XCD swizzle (512 blocks % 8 XCDs == 0): each XCD gets a
  // contiguous 64-block chunk -> 4 resident A-panels in its private L2.
  const int b0  = blockIdx.x;
  const int bid = (b0 & 7) * 64 + (b0 >> 3);

  const u16* A  = (bid < 256) ? A0 : A1;
  const u16* Wm = (bid < 256) ? W0 : W1;
  u16*       C  = (bid < 256) ? C0 : C1;
  const int b2 = bid & 255;
  const int bm = (b2 >> 4) << 8;
  const int bn = (b2 & 15) << 8;

  const int tid = threadIdx.x;
  const int l  = tid & 63;
  const int w  = tid >> 6;   // wave 0..7
  const int wr = w >> 2;     // 0..1  -> M offset wr*128
  const int wc = w & 3;      // 0..3  -> N offset wc*64

  // staging: thread tid, chunk i -> LDS row i*64 + (tid>>3), slot tid&7 (linear);
  // global source column pre-swizzled: k8_src = (tid&7) ^ (row&7)
  const int rb   = tid >> 3;
  const int slot = (tid & 7) ^ (rb & 7);
  const u16* gA = A  + (size_t)(bm + rb) * K + slot * 8;
  const u16* gB = Wm + (size_t)(bn + rb) * K + slot * 8;

  // fragment read addressing (swizzled): elem = row*64 + ((k8 ^ (row&7))*8)
  const int arow = wr * 128 + (l & 15);
  const int brow = wc * 64 + (l & 15);
  const int sl0 = (((l >> 4) + 0) ^ (l & 7)) * 8;  // ks=0: k8 = l>>4
  const int sl1 = (((l >> 4) + 4) ^ (l & 7)) * 8;  // ks=1: k8 = 4 + (l>>4)

  f32x4 acc[8][4];
#pragma unroll
  for (int i = 0; i < 8; ++i)
#pragma unroll
    for (int j = 0; j < 4; ++j) acc[i][j] = (f32x4){0.f, 0.f, 0.f, 0.f};

  // prologue: stage K-tile 0 into buffer 0 (8 loads in flight, NO drain)
  STAGE_A(0, 0)
  STAGE_B(0, 0)

  for (int t = 0; t < NT - 1; ++t) {
    const int cur = t & 1, nxt = cur ^ 1;
    const int kn = (t + 1) << 6;
    const u16* sa = sA[cur];
    const u16* sb = sB[cur];
    bf16x8 q0, q1, q2, q3;

    STAGE_A(nxt, kn)                                  // outstanding: 8 + 4
    asm volatile("s_waitcnt vmcnt(4)" ::: "memory");  // tile t landed; A(t+1) in flight
    __builtin_amdgcn_s_barrier();
    PHASE_NOBAR(0, sl0, 1)                            // Q1: mi 0-3, ks 0
    __builtin_amdgcn_s_barrier();
    STAGE_B(nxt, kn)                                  // outstanding: <= 8
    PHASE(4, sl0, 0)                                  // Q2: mi 4-7, ks 0
    __builtin_amdgcn_s_barrier();
    PHASE(0, sl1, 1)                                  // Q3: mi 0-3, ks 1
    __builtin_amdgcn_s_barrier();
    PHASE(4, sl1, 0)                                  // Q4: mi 4-7, ks 1
    // no drain here: next iter's vmcnt(4)+barrier orders everything
  }

  {  // peeled last tile (t = NT-1): nothing left to prefetch
    const u16* sa = sA[(NT - 1) & 1];
    const u16* sb = sB[(NT - 1) & 1];
    bf16x8 q0, q1, q2, q3;
    asm volatile("s_waitcnt vmcnt(0)" ::: "memory");
    __builtin_amdgcn_s_barrier();
    PHASE_NOBAR(0, sl0, 1)
    __builtin_amdgcn_s_barrier();
    PHASE(4, sl0, 0)
    __builtin_amdgcn_s_barrier();
    PHASE(0, sl1, 1)
    __builtin_amdgcn_s_barrier();
    PHASE(4, sl1, 0)
  }

  // C write: col = lane&15, row = (lane>>4)*4 + reg  (m89/m91-verified layout)
  const int ccol = bn + wc * 64 + (l & 15);
  const int crow = bm + wr * 128 + (l >> 4) * 4;
#pragma unroll
  for (int mi = 0; mi < 8; ++mi) {
#pragma unroll
    for (int ni = 0; ni < 4; ++ni) {
      int col = ccol + ni * 16;
#pragma unroll
      for (int r = 0; r < 4; ++r) {
        int row = crow + mi * 16 + r;
        C[(size_t)row * N + col] = f2bf(acc[mi][ni][r]);
      }
    }
  }
}

// ---------------- fused LN(ig) + LN(hg) + gates + cell-LN + outputs ----------
__global__ __launch_bounds__(256) void lstm_epilogue(
    const u16* __restrict__ ig, const u16* __restrict__ hg,
    const float* __restrict__ cx,
    const float* __restrict__ gi, const float* __restrict__ bi,
    const float* __restrict__ gh, const float* __restrict__ bh,
    const float* __restrict__ gc, const float* __restrict__ bc,
    float* __restrict__ out)
{
  const int b = blockIdx.x;
  const int t = threadIdx.x;
  const u16* igr = ig + (size_t)b * 4096;
  const u16* hgr = hg + (size_t)b * 4096;

  __shared__ float redbuf[16];

  float iv[16], hv[16];
  float s_i = 0.f, q_i = 0.f, s_h = 0.f, q_h = 0.f;
#pragma unroll
  for (int i = 0; i < 16; ++i) {
    float a = bf2f(igr[t + 256 * i]);
    float c = bf2f(hgr[t + 256 * i]);
    iv[i] = a; hv[i] = c;
    s_i += a; q_i += a * a; s_h += c; q_h += c * c;
  }
#pragma unroll
  for (int off = 32; off > 0; off >>= 1) {
    s_i += __shfl_xor(s_i, off);
    q_i += __shfl_xor(q_i, off);
    s_h += __shfl_xor(s_h, off);
    q_h += __shfl_xor(q_h, off);
  }
  {
    int wv = t >> 6;
    if ((t & 63) == 0) {
      redbuf[wv] = s_i; redbuf[wv + 4] = q_i;
      redbuf[wv + 8] = s_h; redbuf[wv + 12] = q_h;
    }
    __syncthreads();
    s_i = redbuf[0] + redbuf[1] + redbuf[2] + redbuf[3];
    q_i = redbuf[4] + redbuf[5] + redbuf[6] + redbuf[7];
    s_h = redbuf[8] + redbuf[9] + redbuf[10] + redbuf[11];
    q_h = redbuf[12] + redbuf[13] + redbuf[14] + redbuf[15];
    __syncthreads();
  }
  const float inv4096 = 1.0f / 4096.0f;
  float mu_i = s_i * inv4096;
  float rs_i = rsqrtf(q_i * inv4096 - mu_i * mu_i + EPS);
  float mu_h = s_h * inv4096;
  float rs_h = rsqrtf(q_h * inv4096 - mu_h * mu_h + EPS);

  float c_pre[4], og[4];
  float s_c = 0.f, q_c = 0.f;
#pragma unroll
  for (int i = 0; i < 4; ++i) {
    int h = t + 256 * i;
    float g_in = ((iv[i]      - mu_i) * rs_i * gi[h]        + bi[h]) +
                 ((hv[i]      - mu_h) * rs_h * gh[h]        + bh[h]);
    float g_fg = ((iv[i + 4]  - mu_i) * rs_i * gi[h + 1024] + bi[h + 1024]) +
                 ((hv[i + 4]  - mu_h) * rs_h * gh[h + 1024] + bh[h + 1024]);
    float g_cl = ((iv[i + 8]  - mu_i) * rs_i * gi[h + 2048] + bi[h + 2048]) +
                 ((hv[i + 8]  - mu_h) * rs_h * gh[h + 2048] + bh[h + 2048]);
    float g_og = ((iv[i + 12] - mu_i) * rs_i * gi[h + 3072] + bi[h + 3072]) +
                 ((hv[i + 12] - mu_h) * rs_h * gh[h + 3072] + bh[h + 3072]);
    float in_s = sigmoidf(g_in);
    float fg_s = sigmoidf(g_fg);
    float cl_t = tanhf(g_cl);
    og[i] = sigmoidf(g_og);
    c_pre[i] = fg_s * cx[(size_t)b * 1024 + h] + in_s * cl_t;
    s_c += c_pre[i]; q_c += c_pre[i] * c_pre[i];
  }
#pragma unroll
  for (int off = 32; off > 0; off >>= 1) {
    s_c += __shfl_xor(s_c, off);
    q_c += __shfl_xor(q_c, off);
  }
  {
    int wv = t >> 6;
    if ((t & 63) == 0) { redbuf[wv] = s_c; redbuf[wv + 4] = q_c; }
    __syncthreads();
    s_c = redbuf[0] + redbuf[1] + redbuf[2] + redbuf[3];
    q_c = redbuf[4] + redbuf[5] + redbuf[6] + redbuf[7];
  }
  const float inv1024 = 1.0f / 1024.0f;
  float mu_c = s_c * inv1024;
  float rs_c = rsqrtf(q_c * inv1024 - mu_c * mu_c + EPS);

  const size_t BH = (size_t)4096 * 1024;
#pragma unroll
  for (int i = 0; i < 4; ++i) {
    int h = t + 256 * i;
    float cy = (c_pre[i] - mu_c) * rs_c * gc[h] + bc[h];
    float hy = og[i] * tanhf(cy);
    size_t o = (size_t)b * 1024 + h;
    out[o] = hy;
    out[BH + o] = hy;
    out[2 * BH + o] = cy;
  }
}

extern "C" void kernel_launch(void* const* d_in, const int* in_sizes, int n_in,
                              void* d_out, int out_size, void* d_ws, size_t ws_size,
                              hipStream_t stream) {
  const float* input = (const float*)d_in[0];
  const float* hx    = (const float*)d_in[1];
  const float* cx    = (const float*)d_in[2];
  const float* wih   = (const float*)d_in[3];
  const float* whh   = (const float*)d_in[4];
  const float* gi    = (const float*)d_in[5];
  const float* bi    = (const float*)d_in[6];
  const float* gh    = (const float*)d_in[7];
  const float* bh    = (const float*)d_in[8];
  const float* gc    = (const float*)d_in[9];
  const float* bc    = (const float*)d_in[10];
  float* out = (float*)d_out;

  char* wsp = (char*)d_ws;
  u16* a_bf  = (u16*)(wsp);
  u16* h_bf  = (u16*)(wsp + ((size_t)8  << 20));
  u16* wi_bf = (u16*)(wsp + ((size_t)16 << 20));
  u16* wh_bf = (u16*)(wsp + ((size_t)24 << 20));
  u16* ig_bf = (u16*)(wsp + ((size_t)32 << 20));
  u16* hg_bf = (u16*)(wsp + ((size_t)64 << 20));

  const int nper = 4096 * 1024;
  dim3 cgrid(nper / 8 / 256, 4);
  cast4_f32_bf16<<<cgrid, 256, 0, stream>>>(input, hx, wih, whh,
                                            a_bf, h_bf, wi_bf, wh_bf, nper);

  gemm256_dual<<<512, 512, 0, stream>>>(a_bf, wi_bf, ig_bf,
                                        h_bf, wh_bf, hg_bf);

  lstm_epilogue<<<4096, 256, 0, stream>>>(ig_bf, hg_bf, cx,
                                          gi, bi, gh, bh, gc, bc, out);
}